// Round 1
// baseline (358.841 us; speedup 1.0000x reference)
//
#include <hip/hip_runtime.h>
#include <hip/hip_bf16.h>

#define RES 300
#define NPLANE (RES * RES)   // 90000
#define NCH 64
#define NC_A 48
#define APP_DIM 27
#define KPAD 160             // 144 padded to 160 (5 k-steps of 32)

// ---------------------------------------------------------------------------
// Kernel 1: transpose plane_coef (3,64,300,300) f32 -> Tp (3,90000,64) bf16
// LDS-tiled so both global read and global write are coalesced.
// ---------------------------------------------------------------------------
__global__ __launch_bounds__(256) void transpose_plane(
    const float* __restrict__ in, __hip_bfloat16* __restrict__ out) {
  __shared__ float tile[64][65];   // +1 pad: conflict-free column reads
  const int i    = blockIdx.y;
  const int p0   = blockIdx.x * 64;
  const int tid  = threadIdx.x;
  const int lane = tid & 63;
  const int grp  = tid >> 6;       // 0..3

  #pragma unroll
  for (int r = 0; r < 16; ++r) {
    int c = grp * 16 + r;
    int p = p0 + lane;
    if (p < NPLANE) tile[c][lane] = in[(size_t)(i * 64 + c) * NPLANE + p];
  }
  __syncthreads();
  #pragma unroll
  for (int r = 0; r < 16; ++r) {
    int pl = grp * 16 + r;
    int p  = p0 + pl;
    if (p < NPLANE)
      out[((size_t)i * NPLANE + p) * 64 + lane] = __float2bfloat16(tile[lane][pl]);
  }
}

// ---------------------------------------------------------------------------
// Kernel 2: transpose line_coef (3,64,300,1) f32 -> Tl (3,300,64) f32 (tiny)
// ---------------------------------------------------------------------------
__global__ __launch_bounds__(256) void transpose_line(
    const float* __restrict__ in, float* __restrict__ out) {
  int idx = blockIdx.x * 256 + threadIdx.x;   // exactly 57600 = 225*256
  int c = idx & 63;
  int y = (idx >> 6) % RES;
  int i = idx / (64 * RES);
  out[idx] = in[(i * 64 + c) * RES + y];
}

// ---------------------------------------------------------------------------
// Kernel 3: fused gather + blend + sigma + MFMA basis projection.
// Block = 256 threads (4 waves), 64 samples/block, lane = channel.
// ---------------------------------------------------------------------------
typedef __attribute__((ext_vector_type(8))) short short8;
typedef __attribute__((ext_vector_type(4))) float f32x4;

__global__ __launch_bounds__(256) void tensorf_main(
    const float* __restrict__ xyz, const __hip_bfloat16* __restrict__ Tp,
    const float* __restrict__ Tl, const float* __restrict__ W,
    float* __restrict__ out, int n_total) {
  __shared__ __hip_bfloat16 Wb[32 * KPAD];    // [d][k] bf16, padded w/ zeros
  __shared__ __hip_bfloat16 prod[64 * KPAD];  // [s][k] bf16, k-pad zeroed
  __shared__ float cw[64 * 32];               // per-sample coords/weights

  const int tid  = threadIdx.x;
  const int lane = tid & 63;
  const int wave = tid >> 6;
  const int n0   = blockIdx.x * 64;

  // ---- Phase 0a: cooperative load of basis into Wb[d][k] (bf16, zero-pad)
  for (int j = tid; j < 32 * KPAD; j += 256) {
    int d = j / KPAD, k = j % KPAD;
    float v = (d < APP_DIM && k < 144) ? W[d * 144 + k] : 0.f;
    Wb[j] = __float2bfloat16(v);
  }
  // zero the k-pad region of prod (k in [144,160) for all 64 samples)
  for (int j = tid; j < 64 * 16; j += 256) {
    int s = j >> 4, k = 144 + (j & 15);
    prod[s * KPAD + k] = __float2bfloat16(0.f);
  }

  // ---- Phase 0b: per-sample coords (one thread per sample)
  if (tid < 64) {
    int n = n0 + tid;
    float x = 0.f, y = 0.f, z = 0.f;
    if (n < n_total) { x = xyz[3 * n]; y = xyz[3 * n + 1]; z = xyz[3 * n + 2]; }
    float crd[3] = {x, y, z};
    const int m0s[3] = {0, 0, 1}, m1s[3] = {1, 2, 2}, vms[3] = {2, 1, 0};
    float* c = &cw[tid * 32];
    #pragma unroll
    for (int i = 0; i < 3; ++i) {
      float ix = (crd[m0s[i]] + 1.f) * 149.5f;
      float iy = (crd[m1s[i]] + 1.f) * 149.5f;
      float x0f = floorf(ix); x0f = fminf(fmaxf(x0f, 0.f), 298.f);
      float y0f = floorf(iy); y0f = fminf(fmaxf(y0f, 0.f), 298.f);
      float wx = ix - x0f, wy = iy - y0f;
      int x0 = (int)x0f, y0 = (int)y0f;
      int base = (i * NPLANE + y0 * RES + x0) * 64;
      float w00 = (1.f - wx) * (1.f - wy), w01 = wx * (1.f - wy);
      float w10 = (1.f - wx) * wy,         w11 = wx * wy;
      float lv = crd[vms[i]];
      float ly = (lv + 1.f) * 149.5f;
      float ly0f = floorf(ly); ly0f = fminf(fmaxf(ly0f, 0.f), 298.f);
      float lwy = ly - ly0f;
      int lbase = (i * RES + (int)ly0f) * 64;
      if (n >= n_total) { w00 = w01 = w10 = w11 = 0.f; lwy = 0.f; base = 0; lbase = 0; }
      c[i * 8 + 0] = __int_as_float(base);
      c[i * 8 + 1] = w00; c[i * 8 + 2] = w01;
      c[i * 8 + 3] = w10; c[i * 8 + 4] = w11;
      c[i * 8 + 5] = __int_as_float(lbase);
      c[i * 8 + 6] = lwy;
      c[i * 8 + 7] = 0.f;
    }
  }
  __syncthreads();

  // ---- Phase 1: gather + bilinear blend. Each wave: 16 samples, lane = chan.
  for (int s5 = 0; s5 < 16; ++s5) {
    int s = wave * 16 + s5;
    const float4* cwv = (const float4*)&cw[s * 32];
    float dsum = 0.f;
    #pragma unroll
    for (int i = 0; i < 3; ++i) {
      float4 q0 = cwv[i * 2];       // base, w00, w01, w10
      float4 q1 = cwv[i * 2 + 1];   // w11, lbase, lwy, pad
      int base = __float_as_int(q0.x) + lane;
      float f00 = __bfloat162float(Tp[base]);
      float f01 = __bfloat162float(Tp[base + 64]);
      float f10 = __bfloat162float(Tp[base + RES * 64]);
      float f11 = __bfloat162float(Tp[base + RES * 64 + 64]);
      int lbase = __float_as_int(q1.y) + lane;
      float la = Tl[lbase], lb = Tl[lbase + 64];
      float pf = q0.y * f00 + q0.z * f01 + q0.w * f10 + q1.x * f11;
      float lf = la + q1.z * (lb - la);
      float pr = pf * lf;
      if (lane < NC_A) prod[s * KPAD + i * NC_A + lane] = __float2bfloat16(pr);
      else             dsum += pr;   // density channels 48..63
    }
    // sigma: butterfly over the 16-lane group 48..63 (xor masks stay in-group)
    dsum += __shfl_xor(dsum, 1);
    dsum += __shfl_xor(dsum, 2);
    dsum += __shfl_xor(dsum, 4);
    dsum += __shfl_xor(dsum, 8);
    int n = n0 + s;
    if (lane == 48 && n < n_total) out[n] = dsum;
  }
  __syncthreads();

  // ---- Phase 2: app = prod(64x144) @ Wb^T(144x27) via mfma 16x16x32 bf16.
  // Per wave: its 16 samples x 2 n-tiles x 5 k-steps.
  const int srow = lane & 15, quad = lane >> 4;
  f32x4 acc0 = {0.f, 0.f, 0.f, 0.f}, acc1 = {0.f, 0.f, 0.f, 0.f};
  const short* prodS = (const short*)prod;
  const short* WbS   = (const short*)Wb;
  const int arow = (wave * 16 + srow) * KPAD;
  #pragma unroll
  for (int kt = 0; kt < 5; ++kt) {
    int ko = kt * 32 + quad * 8;
    short8 a  = *(const short8*)&prodS[arow + ko];
    short8 b0 = *(const short8*)&WbS[srow * KPAD + ko];
    short8 b1 = *(const short8*)&WbS[(16 + srow) * KPAD + ko];
    acc0 = __builtin_amdgcn_mfma_f32_16x16x32_bf16(a, b0, acc0, 0, 0, 0);
    acc1 = __builtin_amdgcn_mfma_f32_16x16x32_bf16(a, b1, acc1, 0, 0, 0);
  }
  // C/D layout: col(d) = lane&15, row(sample) = quad*4 + reg
  float* outApp = out + n_total;
  #pragma unroll
  for (int r = 0; r < 4; ++r) {
    int n = n0 + wave * 16 + quad * 4 + r;
    if (n < n_total) {
      outApp[(size_t)n * APP_DIM + srow] = acc0[r];
      if (srow < APP_DIM - 16)
        outApp[(size_t)n * APP_DIM + 16 + srow] = acc1[r];
    }
  }
}

// ---------------------------------------------------------------------------
extern "C" void kernel_launch(void* const* d_in, const int* in_sizes, int n_in,
                              void* d_out, int out_size, void* d_ws, size_t ws_size,
                              hipStream_t stream) {
  const float* xyz   = (const float*)d_in[0];
  const float* plane = (const float*)d_in[1];
  const float* line  = (const float*)d_in[2];
  const float* W     = (const float*)d_in[3];
  float* out = (float*)d_out;
  const int N = in_sizes[0] / 3;

  __hip_bfloat16* Tp = (__hip_bfloat16*)d_ws;                       // 34,560,000 B
  float* Tl = (float*)((char*)d_ws + (size_t)3 * NPLANE * 64 * 2);  //    230,400 B

  dim3 tb(256);
  transpose_plane<<<dim3((NPLANE + 63) / 64, 3), tb, 0, stream>>>(plane, Tp);
  transpose_line<<<dim3(225), tb, 0, stream>>>(line, Tl);
  tensorf_main<<<dim3((N + 63) / 64), tb, 0, stream>>>(xyz, Tp, Tl, W, out, N);
}

// Round 2
// 301.131 us; speedup vs baseline: 1.1916x; 1.1916x over previous
//
#include <hip/hip_runtime.h>
#include <hip/hip_bf16.h>

#define RES 300
#define NPLANE (RES * RES)   // 90000
#define NC_A 48
#define APP_DIM 27
#define KDIM 144             // 3 * NC_A
#define KS 168               // prod LDS row stride in shorts: 336 B, 16B-aligned, 2-way banks

// ---------------------------------------------------------------------------
// Kernel 1: transpose plane_coef (3,64,300,300) f32 -> Tp (3,90000,64) bf16
// ---------------------------------------------------------------------------
__global__ __launch_bounds__(256) void transpose_plane(
    const float* __restrict__ in, __hip_bfloat16* __restrict__ out) {
  __shared__ float tile[64][65];
  const int i    = blockIdx.y;
  const int p0   = blockIdx.x * 64;
  const int tid  = threadIdx.x;
  const int lane = tid & 63;
  const int grp  = tid >> 6;

  #pragma unroll
  for (int r = 0; r < 16; ++r) {
    int c = grp * 16 + r;
    int p = p0 + lane;
    tile[c][lane] = (p < NPLANE) ? in[(size_t)(i * 64 + c) * NPLANE + p] : 0.f;
  }
  __syncthreads();
  // packed bf16x2 stores: half-wave covers one p, 2 channels per thread
  const int c2 = (lane & 31) * 2;
  const int dp = lane >> 5;
  #pragma unroll
  for (int r = 0; r < 8; ++r) {
    int pl = grp * 16 + r * 2 + dp;
    int p  = p0 + pl;
    if (p < NPLANE) {
      __hip_bfloat162 v;
      v.x = __float2bfloat16(tile[c2][pl]);
      v.y = __float2bfloat16(tile[c2 + 1][pl]);
      *(__hip_bfloat162*)&out[((size_t)i * NPLANE + p) * 64 + c2] = v;
    }
  }
}

// ---------------------------------------------------------------------------
// Kernel 2: line_coef (3,64,300,1) f32 -> TlP (3,300,64) packed bf16x2 (y, y+1)
// ---------------------------------------------------------------------------
__global__ __launch_bounds__(256) void transpose_line(
    const float* __restrict__ in, __hip_bfloat162* __restrict__ out) {
  int idx = blockIdx.x * 256 + threadIdx.x;   // 57600 = 225*256
  int c = idx & 63;
  int y = (idx >> 6) % RES;
  int i = idx / (64 * RES);
  float a = in[(i * 64 + c) * RES + y];
  int y1 = min(y + 1, RES - 1);
  float b = in[(i * 64 + c) * RES + y1];
  __hip_bfloat162 v;
  v.x = __float2bfloat16(a);
  v.y = __float2bfloat16(b);
  out[idx] = v;
}

// ---------------------------------------------------------------------------
// Kernel 3: pre-pack MFMA B-fragments of basis_W into bf16 (L2-hot, 10 KB).
// layout: (((tile*5 + kt)*64 + lane)*8 + j); value = W[n][k], n=tile*16+(l&15),
// k = kt*32 + (l>>4)*8 + j, zero-padded past n>=27 / k>=144.
// ---------------------------------------------------------------------------
__global__ __launch_bounds__(256) void prep_W(
    const float* __restrict__ W, __hip_bfloat16* __restrict__ Wg) {
  for (int idx = threadIdx.x; idx < 2 * 5 * 64 * 8; idx += 256) {
    int j    = idx & 7;
    int lane = (idx >> 3) & 63;
    int kt   = (idx >> 9) % 5;
    int tile = idx / (5 * 64 * 8);
    int n = tile * 16 + (lane & 15);
    int k = kt * 32 + (lane >> 4) * 8 + j;
    float v = (n < APP_DIM && k < KDIM) ? W[n * KDIM + k] : 0.f;
    Wg[idx] = __float2bfloat16(v);
  }
}

// ---------------------------------------------------------------------------
// Kernel 4: fused gather + blend + sigma + MFMA projection.
// 256 thr (4 waves), 64 samples/block. LDS = 21504 + 3072 = 24576 B -> 6 blk/CU.
// ---------------------------------------------------------------------------
typedef __attribute__((ext_vector_type(8))) short short8;
typedef __attribute__((ext_vector_type(4))) float f32x4;

__global__ __launch_bounds__(256, 6) void tensorf_main(
    const float* __restrict__ xyz, const __hip_bfloat16* __restrict__ Tp,
    const unsigned int* __restrict__ TlP, const __hip_bfloat16* __restrict__ Wg,
    float* __restrict__ out, int n_total) {
  __shared__ __hip_bfloat16 prod[64 * KS];
  __shared__ float cw[64 * 12];

  const int tid  = threadIdx.x;
  const int lane = tid & 63;
  const int wave = tid >> 6;
  const int n0   = blockIdx.x * 64;

  // zero prod k-pad [144,168) : 12 uints per sample row
  for (int j = tid; j < 64 * 12; j += 256) {
    int s = j / 12, kk = (j % 12) * 2;
    *(unsigned int*)&prod[s * KS + KDIM + kk] = 0u;
  }

  // per-sample clamped coords (one thread per sample)
  if (tid < 64) {
    int n = min(n0 + tid, n_total - 1);
    float crd[3] = {xyz[3 * n], xyz[3 * n + 1], xyz[3 * n + 2]};
    const int m0s[3] = {0, 0, 1}, m1s[3] = {1, 2, 2}, vms[3] = {2, 1, 0};
    float* c = &cw[tid * 12];
    #pragma unroll
    for (int i = 0; i < 3; ++i) {
      c[i * 4 + 0] = fminf(fmaxf((crd[m0s[i]] + 1.f) * 149.5f, 0.f), 299.f);
      c[i * 4 + 1] = fminf(fmaxf((crd[m1s[i]] + 1.f) * 149.5f, 0.f), 299.f);
      c[i * 4 + 2] = fminf(fmaxf((crd[vms[i]] + 1.f) * 149.5f, 0.f), 299.f);
      c[i * 4 + 3] = 0.f;
    }
  }
  __syncthreads();

  // ---- Phase 1: gather + blend; wave handles 16 samples, lane = channel
  #pragma unroll 2
  for (int s5 = 0; s5 < 16; ++s5) {
    int s = wave * 16 + s5;
    const float4* cv = (const float4*)&cw[s * 12];
    float dsum = 0.f;
    #pragma unroll
    for (int i = 0; i < 3; ++i) {
      float4 q = cv[i];                       // ix, iy, ly (clamped to [0,299])
      float x0f = fminf(floorf(q.x), 298.f);
      float y0f = fminf(floorf(q.y), 298.f);
      float l0f = fminf(floorf(q.z), 298.f);
      float wx = q.x - x0f, wy = q.y - y0f, lwy = q.z - l0f;
      int base  = ((i * NPLANE + (int)y0f * RES + (int)x0f) << 6) + lane;
      int lbase = ((i * RES + (int)l0f) << 6) + lane;
      float f00 = __bfloat162float(Tp[base]);
      float f01 = __bfloat162float(Tp[base + 64]);
      float f10 = __bfloat162float(Tp[base + RES * 64]);
      float f11 = __bfloat162float(Tp[base + RES * 64 + 64]);
      unsigned int lp = TlP[lbase];
      __hip_bfloat162 lv = *(__hip_bfloat162*)&lp;
      float la = __bfloat162float(lv.x), lb = __bfloat162float(lv.y);
      float pf = (1.f - wx) * (1.f - wy) * f00 + wx * (1.f - wy) * f01 +
                 (1.f - wx) * wy * f10 + wx * wy * f11;
      float lf = la + lwy * (lb - la);
      float pr = pf * lf;
      if (lane < NC_A) prod[s * KS + i * NC_A + lane] = __float2bfloat16(pr);
      else             dsum += pr;            // density channels 48..63
    }
    dsum += __shfl_xor(dsum, 1);
    dsum += __shfl_xor(dsum, 2);
    dsum += __shfl_xor(dsum, 4);
    dsum += __shfl_xor(dsum, 8);
    int n = n0 + s;
    if (lane == 48 && n < n_total) out[n] = dsum;
  }
  __syncthreads();

  // ---- Phase 2: app = prod(64x144) @ W^T via mfma 16x16x32 bf16, B from Wg
  const int srow = lane & 15, quad = lane >> 4;
  f32x4 acc0 = {0.f, 0.f, 0.f, 0.f}, acc1 = {0.f, 0.f, 0.f, 0.f};
  const short* prodS = (const short*)prod;
  const short* WgS   = (const short*)Wg;
  const int arow = (wave * 16 + srow) * KS;
  #pragma unroll
  for (int kt = 0; kt < 5; ++kt) {
    short8 a  = *(const short8*)&prodS[arow + kt * 32 + quad * 8];
    short8 b0 = *(const short8*)&WgS[(kt * 64 + lane) * 8];
    short8 b1 = *(const short8*)&WgS[((5 + kt) * 64 + lane) * 8];
    acc0 = __builtin_amdgcn_mfma_f32_16x16x32_bf16(a, b0, acc0, 0, 0, 0);
    acc1 = __builtin_amdgcn_mfma_f32_16x16x32_bf16(a, b1, acc1, 0, 0, 0);
  }
  // C/D layout: col(d) = lane&15, row(sample) = quad*4 + reg
  float* outApp = out + n_total;
  #pragma unroll
  for (int r = 0; r < 4; ++r) {
    int n = n0 + wave * 16 + quad * 4 + r;
    if (n < n_total) {
      outApp[(size_t)n * APP_DIM + srow] = acc0[r];
      if (srow < APP_DIM - 16)
        outApp[(size_t)n * APP_DIM + 16 + srow] = acc1[r];
    }
  }
}

// ---------------------------------------------------------------------------
extern "C" void kernel_launch(void* const* d_in, const int* in_sizes, int n_in,
                              void* d_out, int out_size, void* d_ws, size_t ws_size,
                              hipStream_t stream) {
  const float* xyz   = (const float*)d_in[0];
  const float* plane = (const float*)d_in[1];
  const float* line  = (const float*)d_in[2];
  const float* W     = (const float*)d_in[3];
  float* out = (float*)d_out;
  const int N = in_sizes[0] / 3;

  char* ws = (char*)d_ws;
  __hip_bfloat16*  Tp = (__hip_bfloat16*)ws;                          // 34,560,000 B
  __hip_bfloat162* Tl = (__hip_bfloat162*)(ws + 34560000);            //    230,400 B
  __hip_bfloat16*  Wg = (__hip_bfloat16*)(ws + 34560000 + 230400);    //     10,240 B

  transpose_plane<<<dim3((NPLANE + 63) / 64, 3), 256, 0, stream>>>(plane, Tp);
  transpose_line<<<225, 256, 0, stream>>>(line, Tl);
  prep_W<<<1, 256, 0, stream>>>(W, Wg);
  tensorf_main<<<(N + 63) / 64, 256, 0, stream>>>(xyz, Tp, (const unsigned int*)Tl, Wg, out, N);
}

// Round 3
// 294.831 us; speedup vs baseline: 1.2171x; 1.0214x over previous
//
#include <hip/hip_runtime.h>
#include <hip/hip_bf16.h>

#define RES 300
#define NPLANE (RES * RES)   // 90000
#define NC_A 48
#define APP_DIM 27
#define KDIM 144             // 3 * NC_A
#define KS 168               // prod LDS row stride in shorts (336 B, 16B-aligned)

// bf16 (packed in uint halves) -> f32
__device__ __forceinline__ float bf_lo(unsigned int u) { return __uint_as_float(u << 16); }
__device__ __forceinline__ float bf_hi(unsigned int u) { return __uint_as_float(u & 0xffff0000u); }

// ---------------------------------------------------------------------------
// Unified prep kernel: 280 blocks.
//   blocks [0,264):  plane transpose (3,64,300,300) f32 -> Tp (3,90000,64) bf16
//                    divergent-row float4 reads (L1 line-efficient),
//                    coalesced 128B bf16 stores. No LDS.
//   blocks [264,279): line transpose -> TlP (3,300,64) packed bf16x2 (y,y+1)
//   block  279:      pre-pack MFMA B-fragments of basis_W (bf16, 10 KB)
// ---------------------------------------------------------------------------
__global__ __launch_bounds__(256) void prep(
    const float* __restrict__ plane, const float* __restrict__ line,
    const float* __restrict__ W,
    __hip_bfloat16* __restrict__ Tp, unsigned int* __restrict__ TlP,
    __hip_bfloat16* __restrict__ Wg) {
  __shared__ unsigned int ltile[64 * 65];
  const int blk = blockIdx.x;
  const int tid = threadIdx.x;

  if (blk < 264) {
    const int lane = tid & 63;                 // lane = channel
    const int wid  = blk * 4 + (tid >> 6);     // global wave id 0..1055
    const int u0   = wid * 64;                 // 64 contiguous p4-units per wave
    for (int t = 0; t < 64; ++t) {
      int u = u0 + t;                          // unit = (i, p/4)
      if (u >= 67500) break;
      int i = (u >= 45000) ? 2 : (u >= 22500 ? 1 : 0);
      int p = (u - i * 22500) * 4;
      const float4 v = *(const float4*)&plane[((size_t)(i * 64 + lane)) * NPLANE + p];
      size_t ob = ((size_t)i * NPLANE + p) * 64 + lane;
      Tp[ob]       = __float2bfloat16(v.x);
      Tp[ob + 64]  = __float2bfloat16(v.y);
      Tp[ob + 128] = __float2bfloat16(v.z);
      Tp[ob + 192] = __float2bfloat16(v.w);
    }
  } else if (blk < 279) {
    const int b  = blk - 264;
    const int i  = b / 5;
    const int y0 = (b % 5) * 64;
    const int yl = tid & 63;
    const int cq = tid >> 6;
    #pragma unroll
    for (int k = 0; k < 16; ++k) {
      int c = cq * 16 + k;
      int y = y0 + yl;
      float a = 0.f, bv = 0.f;
      if (y < RES) {
        const float* row = line + (i * 64 + c) * RES;
        a  = row[y];
        bv = row[min(y + 1, RES - 1)];
      }
      __hip_bfloat162 h;
      h.x = __float2bfloat16(a);
      h.y = __float2bfloat16(bv);
      ltile[yl * 65 + c] = *(unsigned int*)&h;
    }
    __syncthreads();
    #pragma unroll
    for (int k = 0; k < 16; ++k) {
      int ylc = k * 4 + cq;
      int c   = tid & 63;
      int y   = y0 + ylc;
      if (y < RES) TlP[((size_t)i * RES + y) * 64 + c] = ltile[ylc * 65 + c];
    }
  } else {
    // B-fragment pack: (((tile*5+kt)*64+lane)*8+j) = W[n][k], zero-padded
    for (int idx = tid; idx < 2 * 5 * 64 * 8; idx += 256) {
      int j    = idx & 7;
      int lane = (idx >> 3) & 63;
      int kt   = (idx >> 9) % 5;
      int tile = idx / (5 * 64 * 8);
      int n = tile * 16 + (lane & 15);
      int k = kt * 32 + (lane >> 4) * 8 + j;
      float v = (n < APP_DIM && k < KDIM) ? W[n * KDIM + k] : 0.f;
      Wg[idx] = __float2bfloat16(v);
    }
  }
}

// ---------------------------------------------------------------------------
// Main kernel: fused gather + blend + sigma + MFMA projection.
// 256 thr (4 waves), 64 samples/block. Channel-PAIR scheme: lane covers 2
// channels (bf16x2 dword loads); half-waves process 2 samples per iteration.
// LDS = 21504 (prod) + 4608 (cw) = 26112 B -> 6 blocks/CU.
// ---------------------------------------------------------------------------
typedef __attribute__((ext_vector_type(8))) short short8;
typedef __attribute__((ext_vector_type(4))) float f32x4;

__global__ __launch_bounds__(256, 6) void tensorf_main(
    const float* __restrict__ xyz, const unsigned int* __restrict__ TpU,
    const unsigned int* __restrict__ TlP, const __hip_bfloat16* __restrict__ Wg,
    float* __restrict__ out, int n_total) {
  __shared__ __hip_bfloat16 prod[64 * KS];
  __shared__ float cw[64 * 18];

  const int tid  = threadIdx.x;
  const int lane = tid & 63;
  const int wave = tid >> 6;
  const int n0   = blockIdx.x * 64;

  // zero prod k-pad [144,168)
  for (int j = tid; j < 64 * 12; j += 256) {
    int s = j / 12, kk = (j % 12) * 2;
    *(unsigned int*)&prod[s * KS + KDIM + kk] = 0u;
  }

  // Phase 0: per-sample precompute — packed cell/line index + 4 bilinear
  // weights + line weight. 6 floats per plane per sample.
  if (tid < 64) {
    int n = min(n0 + tid, n_total - 1);
    float crd[3] = {xyz[3 * n], xyz[3 * n + 1], xyz[3 * n + 2]};
    const int m0s[3] = {0, 0, 1}, m1s[3] = {1, 2, 2}, vms[3] = {2, 1, 0};
    float* c = &cw[tid * 18];
    #pragma unroll
    for (int i = 0; i < 3; ++i) {
      float ix = fminf(fmaxf((crd[m0s[i]] + 1.f) * 149.5f, 0.f), 299.f);
      float iy = fminf(fmaxf((crd[m1s[i]] + 1.f) * 149.5f, 0.f), 299.f);
      float ly = fminf(fmaxf((crd[vms[i]] + 1.f) * 149.5f, 0.f), 299.f);
      float x0f = fminf(floorf(ix), 298.f);
      float y0f = fminf(floorf(iy), 298.f);
      float l0f = fminf(floorf(ly), 298.f);
      float wx = ix - x0f, wy = iy - y0f, lwy = ly - l0f;
      int cell = i * NPLANE + (int)y0f * RES + (int)x0f;   // < 2^19
      int lidx = i * RES + (int)l0f;                       // < 2^10
      c[i * 6 + 0] = __int_as_float(cell | (lidx << 19));
      c[i * 6 + 1] = (1.f - wx) * (1.f - wy);
      c[i * 6 + 2] = wx * (1.f - wy);
      c[i * 6 + 3] = (1.f - wx) * wy;
      c[i * 6 + 4] = wx * wy;
      c[i * 6 + 5] = lwy;
    }
  }
  __syncthreads();

  // Phase 1: gather + blend; 2 samples/wave-iteration, lane = channel pair
  const int cl   = lane & 31;
  const int half = lane >> 5;
  const int c2   = cl * 2;
  #pragma unroll 2
  for (int it = 0; it < 8; ++it) {
    int s = wave * 16 + it * 2 + half;
    const float* cp = &cw[s * 18];
    float dsum = 0.f;
    #pragma unroll
    for (int i = 0; i < 3; ++i) {
      float2 q0 = *(const float2*)&cp[i * 6];       // pack, w00
      float2 q1 = *(const float2*)&cp[i * 6 + 2];   // w01, w10
      float2 q2 = *(const float2*)&cp[i * 6 + 4];   // w11, lwy
      int pk   = __float_as_int(q0.x);
      int cell = pk & 0x7FFFF;
      int lidx = pk >> 19;
      int bidx = cell * 32 + cl;                    // uint index into TpU
      unsigned int u00 = TpU[bidx];
      unsigned int u01 = TpU[bidx + 32];
      unsigned int u10 = TpU[bidx + RES * 32];
      unsigned int u11 = TpU[bidx + RES * 32 + 32];
      uint2 ul = *(const uint2*)&TlP[(lidx << 6) + c2];
      float pf_l = q0.y * bf_lo(u00) + q1.x * bf_lo(u01) +
                   q1.y * bf_lo(u10) + q2.x * bf_lo(u11);
      float pf_h = q0.y * bf_hi(u00) + q1.x * bf_hi(u01) +
                   q1.y * bf_hi(u10) + q2.x * bf_hi(u11);
      float lal = bf_lo(ul.x), lbl = bf_hi(ul.x);
      float lah = bf_lo(ul.y), lbh = bf_hi(ul.y);
      float lf_l = lal + q2.y * (lbl - lal);
      float lf_h = lah + q2.y * (lbh - lah);
      float prl = pf_l * lf_l, prh = pf_h * lf_h;
      if (cl < 24) {    // app channel pairs 0..46
        __hip_bfloat162 h;
        h.x = __float2bfloat16(prl);
        h.y = __float2bfloat16(prh);
        *(unsigned int*)&prod[s * KS + i * NC_A + c2] = *(unsigned int*)&h;
      } else {          // density channel pairs 48..62
        dsum += prl + prh;
      }
    }
    // butterfly within the 8-lane density group (aligned: 24..31 / 56..63)
    dsum += __shfl_xor(dsum, 1);
    dsum += __shfl_xor(dsum, 2);
    dsum += __shfl_xor(dsum, 4);
    int n = n0 + s;
    if (cl == 24 && n < n_total) out[n] = dsum;
  }
  __syncthreads();

  // Phase 2: app = prod(64x144) @ W^T via mfma 16x16x32 bf16, B from Wg
  const int srow = lane & 15, quad = lane >> 4;
  f32x4 acc0 = {0.f, 0.f, 0.f, 0.f}, acc1 = {0.f, 0.f, 0.f, 0.f};
  const short* prodS = (const short*)prod;
  const short* WgS   = (const short*)Wg;
  const int arow = (wave * 16 + srow) * KS;
  #pragma unroll
  for (int kt = 0; kt < 5; ++kt) {
    short8 a  = *(const short8*)&prodS[arow + kt * 32 + quad * 8];
    short8 b0 = *(const short8*)&WgS[(kt * 64 + lane) * 8];
    short8 b1 = *(const short8*)&WgS[((5 + kt) * 64 + lane) * 8];
    acc0 = __builtin_amdgcn_mfma_f32_16x16x32_bf16(a, b0, acc0, 0, 0, 0);
    acc1 = __builtin_amdgcn_mfma_f32_16x16x32_bf16(a, b1, acc1, 0, 0, 0);
  }
  // C/D layout: col(d) = lane&15, row(sample) = quad*4 + reg
  float* outApp = out + n_total;
  #pragma unroll
  for (int r = 0; r < 4; ++r) {
    int n = n0 + wave * 16 + quad * 4 + r;
    if (n < n_total) {
      outApp[(size_t)n * APP_DIM + srow] = acc0[r];
      if (srow < APP_DIM - 16)
        outApp[(size_t)n * APP_DIM + 16 + srow] = acc1[r];
    }
  }
}

// ---------------------------------------------------------------------------
extern "C" void kernel_launch(void* const* d_in, const int* in_sizes, int n_in,
                              void* d_out, int out_size, void* d_ws, size_t ws_size,
                              hipStream_t stream) {
  const float* xyz   = (const float*)d_in[0];
  const float* plane = (const float*)d_in[1];
  const float* line  = (const float*)d_in[2];
  const float* W     = (const float*)d_in[3];
  float* out = (float*)d_out;
  const int N = in_sizes[0] / 3;

  char* ws = (char*)d_ws;
  __hip_bfloat16* Tp  = (__hip_bfloat16*)ws;                        // 34,560,000 B
  unsigned int*   TlP = (unsigned int*)(ws + 34560000);             //    230,400 B
  __hip_bfloat16* Wg  = (__hip_bfloat16*)(ws + 34560000 + 230400);  //     10,240 B

  prep<<<280, 256, 0, stream>>>(plane, line, W, Tp, TlP, Wg);
  tensorf_main<<<(N + 63) / 64, 256, 0, stream>>>(
      xyz, (const unsigned int*)Tp, TlP, Wg, out, N);
}

// Round 4
// 227.762 us; speedup vs baseline: 1.5755x; 1.2945x over previous
//
#include <hip/hip_runtime.h>
#include <hip/hip_bf16.h>

#define RES 300
#define NPLANE (RES * RES)   // 90000
#define NC_A 48
#define APP_DIM 27
#define KDIM 144             // 3 * NC_A
#define KS 168               // prod LDS row stride in shorts (336 B, 16B-aligned)

#define NPBLK 4219           // plane-transpose blocks: 1,080,000 threads / 256

// bf16 (packed in uint halves) -> f32
__device__ __forceinline__ float bf_lo(unsigned int u) { return __uint_as_float(u << 16); }
__device__ __forceinline__ float bf_hi(unsigned int u) { return __uint_as_float(u & 0xffff0000u); }

// ---------------------------------------------------------------------------
// Unified prep kernel.
//   blocks [0,4219):    plane transpose (3,64,300,300) f32 -> Tp (3,90000,64)
//                       bf16, register-only 4x4 micro-transpose: dense 64B
//                       read segments, dense 128B store segments, no LDS.
//   blocks [4219,4234): line transpose -> TlP (3,300,64) packed bf16x2 (y,y+1)
//   block  4234:        pre-pack MFMA B-fragments of basis_W (bf16, 10 KB)
// ---------------------------------------------------------------------------
__global__ __launch_bounds__(256) void prep(
    const float* __restrict__ plane, const float* __restrict__ line,
    const float* __restrict__ W,
    uint2* __restrict__ TpV, unsigned int* __restrict__ TlP,
    __hip_bfloat16* __restrict__ Wg) {
  __shared__ unsigned int ltile[64 * 65];
  const int blk = blockIdx.x;
  const int tid = threadIdx.x;

  if (blk < NPBLK) {
    int flat = blk * 256 + tid;          // one thread = 4c x 4p micro-tile
    if (flat < 1080000) {
      int c4   = flat & 15;              // channel quad 0..15
      int rest = flat >> 4;              // 0..67499 : (i, p/4)
      int i  = (rest >= 45000) ? 2 : (rest >= 22500 ? 1 : 0);
      int p0 = (rest - i * 22500) * 4;
      const float* src = plane + (size_t)(i * 64 + c4 * 4) * NPLANE + p0;
      float4 r0 = *(const float4*)(src);
      float4 r1 = *(const float4*)(src + NPLANE);
      float4 r2 = *(const float4*)(src + 2 * NPLANE);
      float4 r3 = *(const float4*)(src + 3 * NPLANE);
      const float* rr[4] = {&r0.x, &r1.x, &r2.x, &r3.x};
      #pragma unroll
      for (int k = 0; k < 4; ++k) {
        __hip_bfloat162 h0, h1;
        h0.x = __float2bfloat16(rr[0][k]);
        h0.y = __float2bfloat16(rr[1][k]);
        h1.x = __float2bfloat16(rr[2][k]);
        h1.y = __float2bfloat16(rr[3][k]);
        uint2 u;
        u.x = *(unsigned int*)&h0;
        u.y = *(unsigned int*)&h1;
        TpV[((size_t)i * NPLANE + p0 + k) * 16 + c4] = u;
      }
    }
  } else if (blk < NPBLK + 15) {
    const int b  = blk - NPBLK;
    const int i  = b / 5;
    const int y0 = (b % 5) * 64;
    const int yl = tid & 63;
    const int cq = tid >> 6;
    #pragma unroll
    for (int k = 0; k < 16; ++k) {
      int c = cq * 16 + k;
      int y = y0 + yl;
      float a = 0.f, bv = 0.f;
      if (y < RES) {
        const float* row = line + (i * 64 + c) * RES;
        a  = row[y];
        bv = row[min(y + 1, RES - 1)];
      }
      __hip_bfloat162 h;
      h.x = __float2bfloat16(a);
      h.y = __float2bfloat16(bv);
      ltile[yl * 65 + c] = *(unsigned int*)&h;
    }
    __syncthreads();
    #pragma unroll
    for (int k = 0; k < 16; ++k) {
      int ylc = k * 4 + cq;
      int c   = tid & 63;
      int y   = y0 + ylc;
      if (y < RES) TlP[((size_t)i * RES + y) * 64 + c] = ltile[ylc * 65 + c];
    }
  } else {
    // B-fragment pack: (((tile*5+kt)*64+lane)*8+j) = W[n][k], zero-padded
    for (int idx = tid; idx < 2 * 5 * 64 * 8; idx += 256) {
      int j    = idx & 7;
      int lane = (idx >> 3) & 63;
      int kt   = (idx >> 9) % 5;
      int tile = idx / (5 * 64 * 8);
      int n = tile * 16 + (lane & 15);
      int k = kt * 32 + (lane >> 4) * 8 + j;
      float v = (n < APP_DIM && k < KDIM) ? W[n * KDIM + k] : 0.f;
      Wg[idx] = __float2bfloat16(v);
    }
  }
}

// ---------------------------------------------------------------------------
// Main kernel: fused gather + blend + sigma + MFMA projection.
// 256 thr (4 waves), 64 samples/block. Channel-PAIR scheme: lane covers 2
// channels (bf16x2 dword loads); half-waves process 2 samples per iteration.
// All 15 gather loads of an iteration are issued before any blend (batched
// into register arrays) so ~15-30 loads/wave stay in flight.
// LDS = 21504 (prod) + 4608 (cw) = 26112 B -> 6 blocks/CU.
// ---------------------------------------------------------------------------
typedef __attribute__((ext_vector_type(8))) short short8;
typedef __attribute__((ext_vector_type(4))) float f32x4;

__global__ __launch_bounds__(256, 6) void tensorf_main(
    const float* __restrict__ xyz, const unsigned int* __restrict__ TpU,
    const unsigned int* __restrict__ TlP, const __hip_bfloat16* __restrict__ Wg,
    float* __restrict__ out, int n_total) {
  __shared__ __hip_bfloat16 prod[64 * KS];
  __shared__ float cw[64 * 18];

  const int tid  = threadIdx.x;
  const int lane = tid & 63;
  const int wave = tid >> 6;
  const int n0   = blockIdx.x * 64;

  // zero prod k-pad [144,168)
  for (int j = tid; j < 64 * 12; j += 256) {
    int s = j / 12, kk = (j % 12) * 2;
    *(unsigned int*)&prod[s * KS + KDIM + kk] = 0u;
  }

  // Phase 0: per-sample precompute — packed cell/line index + 4 bilinear
  // weights + line weight. 6 floats per plane per sample.
  if (tid < 64) {
    int n = min(n0 + tid, n_total - 1);
    float crd[3] = {xyz[3 * n], xyz[3 * n + 1], xyz[3 * n + 2]};
    const int m0s[3] = {0, 0, 1}, m1s[3] = {1, 2, 2}, vms[3] = {2, 1, 0};
    float* c = &cw[tid * 18];
    #pragma unroll
    for (int i = 0; i < 3; ++i) {
      float ix = fminf(fmaxf((crd[m0s[i]] + 1.f) * 149.5f, 0.f), 299.f);
      float iy = fminf(fmaxf((crd[m1s[i]] + 1.f) * 149.5f, 0.f), 299.f);
      float ly = fminf(fmaxf((crd[vms[i]] + 1.f) * 149.5f, 0.f), 299.f);
      float x0f = fminf(floorf(ix), 298.f);
      float y0f = fminf(floorf(iy), 298.f);
      float l0f = fminf(floorf(ly), 298.f);
      float wx = ix - x0f, wy = iy - y0f, lwy = ly - l0f;
      int cell = i * NPLANE + (int)y0f * RES + (int)x0f;   // < 2^19
      int lidx = i * RES + (int)l0f;                       // < 2^10
      c[i * 6 + 0] = __int_as_float(cell | (lidx << 19));
      c[i * 6 + 1] = (1.f - wx) * (1.f - wy);
      c[i * 6 + 2] = wx * (1.f - wy);
      c[i * 6 + 3] = (1.f - wx) * wy;
      c[i * 6 + 4] = wx * wy;
      c[i * 6 + 5] = lwy;
    }
  }
  __syncthreads();

  // Phase 1: gather + blend; 2 samples/wave-iteration, lane = channel pair
  const int cl   = lane & 31;
  const int half = lane >> 5;
  const int c2   = cl * 2;
  #pragma unroll 2
  for (int it = 0; it < 8; ++it) {
    int s = wave * 16 + it * 2 + half;
    const float* cp = &cw[s * 18];

    // -- batched load phase: issue all 15 VMEM ops before any use
    unsigned int u00[3], u01[3], u10[3], u11[3];
    uint2 ul[3];
    float wgt[3][5];
    #pragma unroll
    for (int i = 0; i < 3; ++i) {
      float2 q0 = *(const float2*)&cp[i * 6];       // pack, w00
      float2 q1 = *(const float2*)&cp[i * 6 + 2];   // w01, w10
      float2 q2 = *(const float2*)&cp[i * 6 + 4];   // w11, lwy
      int pk   = __float_as_int(q0.x);
      int cell = pk & 0x7FFFF;
      int lidx = pk >> 19;
      int bidx = cell * 32 + cl;                    // uint index into TpU
      u00[i] = TpU[bidx];
      u01[i] = TpU[bidx + 32];
      u10[i] = TpU[bidx + RES * 32];
      u11[i] = TpU[bidx + RES * 32 + 32];
      ul[i]  = *(const uint2*)&TlP[(lidx << 6) + c2];
      wgt[i][0] = q0.y; wgt[i][1] = q1.x; wgt[i][2] = q1.y;
      wgt[i][3] = q2.x; wgt[i][4] = q2.y;
    }

    // -- blend phase
    float dsum = 0.f;
    #pragma unroll
    for (int i = 0; i < 3; ++i) {
      float pf_l = wgt[i][0] * bf_lo(u00[i]) + wgt[i][1] * bf_lo(u01[i]) +
                   wgt[i][2] * bf_lo(u10[i]) + wgt[i][3] * bf_lo(u11[i]);
      float pf_h = wgt[i][0] * bf_hi(u00[i]) + wgt[i][1] * bf_hi(u01[i]) +
                   wgt[i][2] * bf_hi(u10[i]) + wgt[i][3] * bf_hi(u11[i]);
      float lal = bf_lo(ul[i].x), lbl = bf_hi(ul[i].x);
      float lah = bf_lo(ul[i].y), lbh = bf_hi(ul[i].y);
      float lf_l = lal + wgt[i][4] * (lbl - lal);
      float lf_h = lah + wgt[i][4] * (lbh - lah);
      float prl = pf_l * lf_l, prh = pf_h * lf_h;
      if (cl < 24) {    // app channel pairs 0..46
        __hip_bfloat162 h;
        h.x = __float2bfloat16(prl);
        h.y = __float2bfloat16(prh);
        *(unsigned int*)&prod[s * KS + i * NC_A + c2] = *(unsigned int*)&h;
      } else {          // density channel pairs 48..62
        dsum += prl + prh;
      }
    }
    // butterfly within the 8-lane density group (aligned: 24..31 / 56..63)
    dsum += __shfl_xor(dsum, 1);
    dsum += __shfl_xor(dsum, 2);
    dsum += __shfl_xor(dsum, 4);
    int n = n0 + s;
    if (cl == 24 && n < n_total) out[n] = dsum;
  }
  __syncthreads();

  // Phase 2: app = prod(64x144) @ W^T via mfma 16x16x32 bf16, B from Wg
  const int srow = lane & 15, quad = lane >> 4;
  f32x4 acc0 = {0.f, 0.f, 0.f, 0.f}, acc1 = {0.f, 0.f, 0.f, 0.f};
  const short* prodS = (const short*)prod;
  const short* WgS   = (const short*)Wg;
  const int arow = (wave * 16 + srow) * KS;
  #pragma unroll
  for (int kt = 0; kt < 5; ++kt) {
    short8 a  = *(const short8*)&prodS[arow + kt * 32 + quad * 8];
    short8 b0 = *(const short8*)&WgS[(kt * 64 + lane) * 8];
    short8 b1 = *(const short8*)&WgS[((5 + kt) * 64 + lane) * 8];
    acc0 = __builtin_amdgcn_mfma_f32_16x16x32_bf16(a, b0, acc0, 0, 0, 0);
    acc1 = __builtin_amdgcn_mfma_f32_16x16x32_bf16(a, b1, acc1, 0, 0, 0);
  }
  // C/D layout: col(d) = lane&15, row(sample) = quad*4 + reg
  float* outApp = out + n_total;
  #pragma unroll
  for (int r = 0; r < 4; ++r) {
    int n = n0 + wave * 16 + quad * 4 + r;
    if (n < n_total) {
      outApp[(size_t)n * APP_DIM + srow] = acc0[r];
      if (srow < APP_DIM - 16)
        outApp[(size_t)n * APP_DIM + 16 + srow] = acc1[r];
    }
  }
}

// ---------------------------------------------------------------------------
extern "C" void kernel_launch(void* const* d_in, const int* in_sizes, int n_in,
                              void* d_out, int out_size, void* d_ws, size_t ws_size,
                              hipStream_t stream) {
  const float* xyz   = (const float*)d_in[0];
  const float* plane = (const float*)d_in[1];
  const float* line  = (const float*)d_in[2];
  const float* W     = (const float*)d_in[3];
  float* out = (float*)d_out;
  const int N = in_sizes[0] / 3;

  char* ws = (char*)d_ws;
  __hip_bfloat16* Tp  = (__hip_bfloat16*)ws;                        // 34,560,000 B
  unsigned int*   TlP = (unsigned int*)(ws + 34560000);             //    230,400 B
  __hip_bfloat16* Wg  = (__hip_bfloat16*)(ws + 34560000 + 230400);  //     10,240 B

  prep<<<NPBLK + 16, 256, 0, stream>>>(plane, line, W, (uint2*)Tp, TlP, Wg);
  tensorf_main<<<(N + 63) / 64, 256, 0, stream>>>(
      xyz, (const unsigned int*)Tp, TlP, Wg, out, N);
}